// Round 4
// baseline (436.105 us; speedup 1.0000x reference)
//
#include <hip/hip_runtime.h>
#include <stdint.h>

// QuantizedLinear: B=4, S=2048, IN=4096, OUT=4096, OUTLIER=128
// Unified int8 path:
//   W8[o,i] = round(w[o, invp[i]] / w_s_o),  w[o,:] = [qw*alpha | fpw] permuted
//   w_s_o   = rowabsmax(w[o,:]) / 127        (per-output-row scale)
//   A8[m,i] = round(A[m,i] / s_m),  s_m = rowabsmax / 127
//   out[m,o] = s_m * w_s_o * (A8 . W8^T)[m,o] + bias[o]
#define IN_F  4096
#define OUT_F 4096
#define OUTL  128
#define QIN   (IN_F - OUTL)   // 3968
#define MTOT  8192            // B*S
#define BM 256
#define BN 256
#define BKB 128               // K-bytes per K-tile (two 64B K-half planes)
#define NKT (IN_F / BKB)      // 32 K-tiles

typedef unsigned short u16;
typedef int i32x4 __attribute__((ext_vector_type(4)));

// Padded LDS address for the weight gather: +4 floats per 32.
// Gather sources je are near-consecutive (je ~ 16*lane + c), so padded lane
// stride ~18 mod 32 -> <=2-way bank alias (free, m136). Unpadded would be
// 16*lane -> 2 banks for 64 lanes (32-way). Pad of 4 keeps float4 stores
// aligned.
#define QPAD(j) ((j) + (((j) >> 5) << 2))

// ---------------------------------------------------------------------------
// Fused prep (unchanged from round 3: measured -12 us vs round 0).
// ---------------------------------------------------------------------------
__global__ __launch_bounds__(256) void prep_fused(
    const float* __restrict__ A, signed char* __restrict__ A8,
    float* __restrict__ s_arr,
    const float* __restrict__ qw, const float* __restrict__ fpw,
    const float* __restrict__ alpha, const int* __restrict__ invp,
    signed char* __restrict__ W8, float* __restrict__ t_arr) {
  const int tid = threadIdx.x;
  __shared__ float red[4];

  if (blockIdx.x >= OUT_F) {
    // ---- activation row: absmax -> s_m, quantize to int8 ----
    const int m = blockIdx.x - OUT_F;
    const float* row = A + (size_t)m * IN_F;
    float4 v[4];
    float amax = 0.f;
#pragma unroll
    for (int k = 0; k < 4; ++k) {
      v[k] = ((const float4*)row)[k * 256 + tid];
      amax = fmaxf(amax, fmaxf(fmaxf(fabsf(v[k].x), fabsf(v[k].y)),
                               fmaxf(fabsf(v[k].z), fabsf(v[k].w))));
    }
#pragma unroll
    for (int off = 32; off; off >>= 1)
      amax = fmaxf(amax, __shfl_xor(amax, off, 64));
    if ((tid & 63) == 0) red[tid >> 6] = amax;
    __syncthreads();
    amax = fmaxf(fmaxf(red[0], red[1]), fmaxf(red[2], red[3]));
    const float inv = 127.f / amax;
    if (tid == 0) s_arr[m] = amax / 127.f;
#pragma unroll
    for (int k = 0; k < 4; ++k) {
      const int q0 = __float2int_rn(v[k].x * inv);
      const int q1 = __float2int_rn(v[k].y * inv);
      const int q2 = __float2int_rn(v[k].z * inv);
      const int q3 = __float2int_rn(v[k].w * inv);
      const uint32_t p = (q0 & 255) | ((q1 & 255) << 8) |
                         ((q2 & 255) << 16) | ((uint32_t)(q3 & 255) << 24);
      ((uint32_t*)A8)[(size_t)m * (IN_F / 4) + k * 256 + tid] = p;
    }
  } else {
    // ---- weight row: stage qw/fpw in LDS (padded), rowabsmax of
    //      [qw*a | fpw], permuted gather, quantize to int8 ----
    const int o = blockIdx.x;
    __shared__ float qs[QIN + ((QIN >> 5) << 2)];  // 4464 floats, padded
    __shared__ float fs[OUTL];

    int4 jj[4];
#pragma unroll
    for (int q = 0; q < 4; ++q) jj[q] = ((const int4*)invp)[tid * 4 + q];

    const float a = alpha[o];
    float amax = 0.f;

    float4 f;
    if (tid < OUTL / 4) f = ((const float4*)(fpw + (size_t)o * OUTL))[tid];

    const float4* qrow = (const float4*)(qw + (size_t)o * QIN);
#pragma unroll
    for (int k = 0; k < 4; ++k) {
      const int idx = k * 256 + tid;
      if (idx < QIN / 4) {
        const float4 q = qrow[idx];
        ((float4*)&qs[idx * 4 + ((idx >> 3) << 2)])[0] = q;
        const float qm = fmaxf(fmaxf(fabsf(q.x), fabsf(q.y)),
                               fmaxf(fabsf(q.z), fabsf(q.w)));
        amax = fmaxf(amax, qm * a);
      }
    }
    if (tid < OUTL / 4) {
      ((float4*)fs)[tid] = f;
      amax = fmaxf(amax, fmaxf(fmaxf(fabsf(f.x), fabsf(f.y)),
                               fmaxf(fabsf(f.z), fabsf(f.w))));
    }
#pragma unroll
    for (int off = 32; off; off >>= 1)
      amax = fmaxf(amax, __shfl_xor(amax, off, 64));
    if ((tid & 63) == 0) red[tid >> 6] = amax;
    __syncthreads();  // also covers qs/fs visibility
    amax = fmaxf(fmaxf(red[0], red[1]), fmaxf(red[2], red[3]));
    const float invws = 127.f / amax;
    if (tid == 0) t_arr[o] = amax / 127.f;

    signed char vals[16];
#pragma unroll
    for (int q = 0; q < 4; ++q) {
      const int j[4] = {jj[q].x, jj[q].y, jj[q].z, jj[q].w};
#pragma unroll
      for (int e = 0; e < 4; ++e) {
        const int je = j[e];
        const float v = (je < QIN) ? qs[QPAD(je)] * a : fs[je - QIN];
        vals[q * 4 + e] = (signed char)__float2int_rn(v * invws);
      }
    }
    ((uint4*)(W8 + (size_t)o * IN_F))[tid] = *(const uint4*)vals;
  }
}

// ---------------------------------------------------------------------------
// GEMM: 256x256 tile, 8 waves (2M x 4N), 8-PHASE schedule (m201 port to i8).
//
// Per K-tile (128 B of K): 2 K-half planes per operand (all 256 rows x 64 B).
// 4 phases, each = { 4-8 ds_read_b128 ; stage ONE plane of tile kt+1
// (2 GLDS) ; barrier ; setprio(1) ; 16 MFMA ; setprio(0) ; [vmcnt(4)] ;
// barrier }.  vmcnt is counted, never 0 in the loop:
//   at P3-end outstanding = {A0,B0,A1,B1}(kt+1) = 8 loads; vmcnt(4) completes
//   the 4 oldest = {A0,B0}(kt+1) -> resident for kt+1-P0. Symmetric at P1
//   for {A1,B1}(kt+1) (outstanding then = {A1,B1}(kt+1),{A0,B0}(kt+2)).
// WAR safety: phase-p ds_reads are consumed by phase-p MFMAs (compiler emits
// lgkm waits before use), so reads complete before the closing barrier; any
// wave's overwrite of that plane is >=2 barriers later. sched_barrier(0) on
// both sides of every s_barrier pins code motion (rule #18/#21 discipline).
//
// LDS plane layout: [buf][khalf][row*64 + slot*16], slot = chunk ^ ((row>>1)&3).
// Quarter-wave read check: bank span = 16*(fr&1) + 4*(fq^((fr>>1)&3)) -> 8
// distinct 4-bank spans x 2 lanes = 2-way = free (m136). GLDS dest linear
// (wave-uniform base + lane*16); the swizzle is applied to the per-lane
// GLOBAL source chunk: c = (l&3) ^ ((l>>3)&3)  (guide rule #21).
//
// No XCD swizzle; 2D grid bn-fast: each XCD naturally sees bn = x mod 8 ->
// 2 MB W8 slice, L2-resident (round-2 measured: chunked swizzle doubled FETCH).
// ---------------------------------------------------------------------------
#define GLDS(g, l)                                                              \
  __builtin_amdgcn_global_load_lds(                                             \
      (const __attribute__((address_space(1))) void*)(g),                       \
      (__attribute__((address_space(3))) void*)(l), 16, 0, 0)

#define BAR()                                                                   \
  do {                                                                          \
    __builtin_amdgcn_sched_barrier(0);                                          \
    __builtin_amdgcn_s_barrier();                                               \
    __builtin_amdgcn_sched_barrier(0);                                          \
  } while (0)

__global__ __launch_bounds__(512, 2) void gemm_i8(
    const signed char* __restrict__ A8, const signed char* __restrict__ W8,
    const float* __restrict__ s_arr, const float* __restrict__ t_arr,
    const float* __restrict__ bias, float* __restrict__ C) {
  // [buf][khalf][256 rows x 64 B]
  __shared__ unsigned char As[2][2][256 * 64];  // 64 KB
  __shared__ unsigned char Bs[2][2][256 * 64];  // 64 KB

  const int tid  = threadIdx.x;
  const int wave = tid >> 6;   // 0..7
  const int lane = tid & 63;
  const int bn = blockIdx.x, bm = blockIdx.y;

  const int wm = (wave >> 2) * 128;  // 0 / 128
  const int wn = (wave & 3) * 64;    // 0 / 64 / 128 / 192

  // Staging: wave w covers rows [w*32, w*32+32) of each plane, 2 GLDS per
  // plane (16 rows x 64 B = 1 KB each). Lane l -> row l>>2, slot l&3; the
  // global chunk is pre-swizzled: c = (l&3) ^ ((l>>3)&3).
  const int srow   = wave * 32 + (lane >> 2);
  const int schunk = (lane & 3) ^ ((lane >> 3) & 3);
  const signed char* Ag = A8 + (size_t)(bm * BM + srow) * IN_F + schunk * 16;
  const signed char* Wg = W8 + (size_t)(bn * BN + srow) * IN_F + schunk * 16;
  const int stg = wave * 32 * 64;  // LDS byte offset of this wave's rows

  i32x4 acc[8][4];
#pragma unroll
  for (int mi = 0; mi < 8; ++mi)
#pragma unroll
    for (int ni = 0; ni < 4; ++ni) acc[mi][ni] = (i32x4){0, 0, 0, 0};

  const int fr = lane & 15;  // fragment row (m for A, n for B)
  const int fq = lane >> 4;  // 16B k-chunk within the 64B K-half plane
  const int cswz = (fq ^ ((fr >> 1) & 3)) * 16;

  int aoff[8], boff[4];
#pragma unroll
  for (int mi = 0; mi < 8; ++mi) aoff[mi] = (wm + mi * 16 + fr) * 64 + cswz;
#pragma unroll
  for (int ni = 0; ni < 4; ++ni) boff[ni] = (wn + ni * 16 + fr) * 64 + cswz;

  auto LDA = [&](int buf, int ks, int half, i32x4* af) {
#pragma unroll
    for (int mi = 0; mi < 4; ++mi)
      af[mi] = *(const i32x4*)&As[buf][ks][aoff[half * 4 + mi]];
  };
  auto LDB = [&](int buf, int ks, i32x4* bg) {
#pragma unroll
    for (int ni = 0; ni < 4; ++ni)
      bg[ni] = *(const i32x4*)&Bs[buf][ks][boff[ni]];
  };
  auto MM = [&](int mh, const i32x4* af, const i32x4* bg) {
    __builtin_amdgcn_s_setprio(1);
#pragma unroll
    for (int mi = 0; mi < 4; ++mi)
#pragma unroll
      for (int ni = 0; ni < 4; ++ni)
        acc[mh * 4 + mi][ni] = __builtin_amdgcn_mfma_i32_16x16x64_i8(
            af[mi], bg[ni], acc[mh * 4 + mi][ni], 0, 0, 0);
    __builtin_amdgcn_s_setprio(0);
  };
  // Stage one K-half plane of tile ktn into buffer nbuf (2 GLDS).
  auto STG = [&](int nbuf, int op /*0=A,1=B*/, int ks, int ktn) {
    const signed char* g = (op ? Wg : Ag) + ktn * BKB + ks * 64;
    unsigned char* d = op ? &Bs[nbuf][ks][stg] : &As[nbuf][ks][stg];
    GLDS(g, d);
    GLDS(g + 16 * IN_F, d + 1024);
  };

  // Prologue: tile 0 -> buf 0, full drain (one-time).
  STG(0, 0, 0, 0);
  STG(0, 1, 0, 0);
  STG(0, 0, 1, 0);
  STG(0, 1, 1, 0);
  asm volatile("s_waitcnt vmcnt(0)" ::: "memory");
  BAR();

  for (int kt = 0; kt < NKT - 1; ++kt) {
    const int buf = kt & 1, nbuf = buf ^ 1;
    i32x4 af[4], bg[4];
    // ---- P0: ks0, m-half 0 ----
    LDA(buf, 0, 0, af);
    LDB(buf, 0, bg);
    STG(nbuf, 0, 0, kt + 1);
    BAR();
    MM(0, af, bg);
    BAR();
    // ---- P1: ks0, m-half 1 ----
    LDA(buf, 0, 1, af);
    STG(nbuf, 1, 0, kt + 1);
    BAR();
    MM(1, af, bg);
    asm volatile("s_waitcnt vmcnt(4)" ::: "memory");  // {A1,B1}(kt+1) landed
    BAR();
    // ---- P2: ks1, m-half 0 ----
    LDA(buf, 1, 0, af);
    LDB(buf, 1, bg);
    STG(nbuf, 0, 1, kt + 1);
    BAR();
    MM(0, af, bg);
    BAR();
    // ---- P3: ks1, m-half 1 ----
    LDA(buf, 1, 1, af);
    STG(nbuf, 1, 1, kt + 1);
    BAR();
    MM(1, af, bg);
    asm volatile("s_waitcnt vmcnt(4)" ::: "memory");  // {A0,B0}(kt+1) landed
    BAR();
  }
  // Peeled last tile (kt = NKT-1, buf = 1): no staging.
  {
    i32x4 af[4], bg[4];
    LDA(1, 0, 0, af);
    LDB(1, 0, bg);
    BAR();
    MM(0, af, bg);
    BAR();
    LDA(1, 0, 1, af);
    BAR();
    MM(1, af, bg);
    asm volatile("s_waitcnt vmcnt(0)" ::: "memory");  // {A1,B1}(last) landed
    BAR();
    LDA(1, 1, 0, af);
    LDB(1, 1, bg);
    BAR();
    MM(0, af, bg);
    BAR();
    LDA(1, 1, 1, af);
    BAR();
    MM(1, af, bg);
  }

  // Epilogue: C/D layout col = lane&15 (n), row = (lane>>4)*4 + reg (m).
  float sv[8][4];
#pragma unroll
  for (int mi = 0; mi < 8; ++mi)
#pragma unroll
    for (int rr = 0; rr < 4; ++rr)
      sv[mi][rr] = s_arr[bm * BM + wm + mi * 16 + fq * 4 + rr];

#pragma unroll
  for (int ni = 0; ni < 4; ++ni) {
    const int n = bn * BN + wn + ni * 16 + fr;
    const float tn = t_arr[n];
    const float bv = bias[n];
#pragma unroll
    for (int mi = 0; mi < 8; ++mi) {
      const int m0 = bm * BM + wm + mi * 16 + fq * 4;
#pragma unroll
      for (int rr = 0; rr < 4; ++rr)
        C[(size_t)(m0 + rr) * OUT_F + n] =
            (float)acc[mi][ni][rr] * (sv[mi][rr] * tn) + bv;
    }
  }
}

extern "C" void kernel_launch(void* const* d_in, const int* in_sizes, int n_in,
                              void* d_out, int out_size, void* d_ws, size_t ws_size,
                              hipStream_t stream) {
  const float* input = (const float*)d_in[0];  // (4,2048,4096) fp32
  const float* qw    = (const float*)d_in[1];  // (4096,3968) fp32
  const float* fpw   = (const float*)d_in[2];  // (4096,128) fp32
  const float* alpha = (const float*)d_in[3];  // (4096,1) fp32
  const float* bias  = (const float*)d_in[4];  // (4096,) fp32
  const int*   invp  = (const int*)d_in[5];    // (4096,) int32

  char* ws = (char*)d_ws;
  signed char* A8    = (signed char*)ws;                        // 32 MB
  signed char* W8    = (signed char*)(ws + (32ull << 20));      // 16 MB
  float* s_arr = (float*)(ws + (48ull << 20));                  // 32 KB
  float* t_arr = (float*)(ws + (48ull << 20) + (64ull << 10));  // 16 KB
  float* out = (float*)d_out;

  prep_fused<<<OUT_F + MTOT, 256, 0, stream>>>(input, A8, s_arr, qw, fpw,
                                               alpha, invp, W8, t_arr);

  dim3 ggrid(OUT_F / BN, MTOT / BM);  // (16, 32)
  gemm_i8<<<ggrid, dim3(512), 0, stream>>>(A8, W8, s_arr, t_arr, bias, out);
}